// Round 3
// baseline (476.750 us; speedup 1.0000x reference)
//
#include <hip/hip_runtime.h>

#define VOCAB 128
#define EMB   10
#define HID   20
#define BATCH 256
#define TLEN  2048
// tanh(x) = 1 - 2/(exp(2x)+1); v_exp_f32 computes 2^z, so fold 2*log2(e)
// into W_hh and the P table:  z = PRESCALE * (xw + W_hh h)
#define PRESCALE 2.8853900817779268f

// ---------------------------------------------------------------------------
// Kernel A: P[v][j] = 0.5 * PRESCALE * (b_ih[j] + b_hh[j] + sum_e W_ih[j,e]*emb[v,e])
// NOTE the 0.5: the producer's K-split adds the xw term in BOTH wave halves,
// and the cross-half combine sums them -> full xw restored.
// ---------------------------------------------------------------------------
__global__ __launch_bounds__(256)
void build_table(const float* __restrict__ emb, const float* __restrict__ W_ih,
                 const float* __restrict__ b_ih, const float* __restrict__ b_hh,
                 float* __restrict__ P) {
    int idx = blockIdx.x * blockDim.x + threadIdx.x;
    if (idx < VOCAB * HID) {
        int v = idx / HID, j = idx % HID;
        float acc = b_ih[j] + b_hh[j];
        #pragma unroll
        for (int e = 0; e < EMB; ++e)
            acc = fmaf(W_ih[j * EMB + e], emb[v * EMB + e], acc);
        P[idx] = acc * (0.5f * PRESCALE);
    }
}

// ---------------------------------------------------------------------------
// Fused kernel: one block per batch row, 4 waves.
//   wave 0  : sequential recurrence. K-SPLIT across wave halves:
//             lane j (j<20) owns row j, k=0..9; lane 32+j owns row j, k=10..19.
//             Broadcast of h_k via ds_bpermute with per-half addresses
//             (lower reads lane k, upper reads lane 10+k) -> ONE instruction
//             stream serves both halves: 11 bpermute + 10 fma per step vs the
//             old 20 readlane + 20 fma. Cross-half combine = bpermute(lane^32).
//   waves1-3: consume chunk c-1 while wave 0 produces chunk c (unchanged).
// ---------------------------------------------------------------------------
#define RNN_STEP(XW) { \
    float a0 = (XW), a1 = 0.f; \
    const int hi_ = __float_as_int(h); \
    _Pragma("unroll") \
    for (int i = 0; i < 10; i += 2) { \
        float b0 = __int_as_float(__builtin_amdgcn_ds_bpermute(adr[i],     hi_)); \
        float b1 = __int_as_float(__builtin_amdgcn_ds_bpermute(adr[i + 1], hi_)); \
        a0 = fmaf(w[i], b0, a0); a1 = fmaf(w[i + 1], b1, a1); } \
    float s_ = a0 + a1; \
    float o_ = __int_as_float(__builtin_amdgcn_ds_bpermute(xadr, __float_as_int(s_))); \
    float z_ = s_ + o_; \
    float u_ = __builtin_amdgcn_exp2f(z_); \
    float r_ = __builtin_amdgcn_rcpf(u_ + 1.0f); \
    h = fmaf(-2.0f, r_, 1.0f); }

__global__ __launch_bounds__(256)
void rnn_fused(const int* __restrict__ tokens, const float* __restrict__ W_hh,
               const float* __restrict__ P, const float* __restrict__ W_out,
               const float* __restrict__ b_out, float* __restrict__ out) {
    __shared__ float Pl[VOCAB * HID];               // 10240 B
    __shared__ __align__(16) int tok[TLEN + 16];    //  8256 B (pad for prefetch overrun)
    __shared__ float hbuf[2][64][64];               // 32768 B, row stride 64: only
                                                    // cols 0..19 are consumed
    const int tid  = threadIdx.x;
    const int lane = tid & 63;
    const int wid  = tid >> 6;
    const int b    = blockIdx.x;

    // cooperative staging (all 256 threads)
    for (int i = tid; i < VOCAB * HID; i += 256) Pl[i] = P[i];
    const int4* src = (const int4*)(tokens + (size_t)b * TLEN);
    int4* dst = (int4*)tok;
    for (int i = tid; i < TLEN / 4; i += 256) dst[i] = src[i];
    if (tid < 16) tok[TLEN + tid] = 0;

    // per-role register init (before the staging barrier: global reads only)
    const int jj = lane & 31;
    const int j  = jj < HID ? jj : HID - 1;        // clamped lanes: dup row 19
    const int koff = (lane >= 32) ? 10 : 0;        // which K-half this lane owns
    const int xadr = (lane ^ 32) << 2;             // cross-half combine address
    int   adr[10];
    float w[HID], wB[HID];
    float bo0 = 0.f, bo1 = 0.f;
    if (wid == 0) {
        #pragma unroll
        for (int i = 0; i < 10; ++i) {
            w[i]   = W_hh[j * HID + koff + i] * PRESCALE;
            adr[i] = (koff + i) << 2;              // lower: lane i; upper: lane 10+i
        }
    } else {
        const int v0 = 2 * lane, v1 = 2 * lane + 1;
        #pragma unroll
        for (int k = 0; k < HID; ++k) {
            w[k]  = W_out[v0 * HID + k];
            wB[k] = W_out[v1 * HID + k];
        }
        bo0 = b_out[v0]; bo1 = b_out[v1];
    }
    __syncthreads();

    // producer pipeline prologue: tokens for steps 0..15, xw for steps 0..7
    float h = 0.0f;
    int4 ta, tb, tkc, tkd;
    float xw0[4], xw1[4];
    if (wid == 0) {
        __builtin_amdgcn_s_setprio(1);             // critical-path wave
        ta  = *(const int4*)&tok[0];
        tb  = *(const int4*)&tok[4];
        tkc = *(const int4*)&tok[8];
        tkd = *(const int4*)&tok[12];
        xw0[0] = Pl[ta.x * HID + j]; xw0[1] = Pl[ta.y * HID + j];
        xw0[2] = Pl[ta.z * HID + j]; xw0[3] = Pl[ta.w * HID + j];
        xw1[0] = Pl[tb.x * HID + j]; xw1[1] = Pl[tb.y * HID + j];
        xw1[2] = Pl[tb.z * HID + j]; xw1[3] = Pl[tb.w * HID + j];
    }

    // 33-iteration pipeline: iter c -> wave0 produces chunk c, waves1-3
    // consume chunk c-1 from the other LDS buffer half.
    for (int c = 0; c < 33; ++c) {
        if (wid == 0 && c < 32) {
            float* hb = &hbuf[c & 1][0][lane];
            for (int t8 = 0; t8 < 64; t8 += 8) {
                const int t = c * 64 + t8;
                float* hrow = hb + t8 * 64;
                // ---- group 0: steps t..t+3 ----
                RNN_STEP(xw0[0]); hrow[0 * 64] = h;
                RNN_STEP(xw0[1]); hrow[1 * 64] = h;
                RNN_STEP(xw0[2]); hrow[2 * 64] = h;
                RNN_STEP(xw0[3]); hrow[3 * 64] = h;
                // refill xw0 for steps t+8..t+11 (latency hidden by group 1)
                float n0[4] = {Pl[tkc.x * HID + j], Pl[tkc.y * HID + j],
                               Pl[tkc.z * HID + j], Pl[tkc.w * HID + j]};
                tkc = *(const int4*)&tok[t + 16];
                // ---- group 1: steps t+4..t+7 ----
                RNN_STEP(xw1[0]); hrow[4 * 64] = h;
                RNN_STEP(xw1[1]); hrow[5 * 64] = h;
                RNN_STEP(xw1[2]); hrow[6 * 64] = h;
                RNN_STEP(xw1[3]); hrow[7 * 64] = h;
                // refill xw1 for steps t+12..t+15
                float n1[4] = {Pl[tkd.x * HID + j], Pl[tkd.y * HID + j],
                               Pl[tkd.z * HID + j], Pl[tkd.w * HID + j]};
                tkd = *(const int4*)&tok[t + 20];
                #pragma unroll
                for (int u = 0; u < 4; ++u) { xw0[u] = n0[u]; xw1[u] = n1[u]; }
            }
        }
        if (wid > 0 && c > 0) {
            const int cc = c - 1;
            const float* hb = &hbuf[cc & 1][0][0];
            float* outb = out + ((size_t)b * TLEN + (size_t)cc * 64) * VOCAB + 2 * lane;
            for (int r = wid - 1; r < 64; r += 3) {
                const float* hr = hb + r * 64;
                float a0 = bo0, a1 = bo1;
                #pragma unroll
                for (int k = 0; k < HID; k += 4) {
                    float4 hv = *(const float4*)(hr + k);   // wave-uniform broadcast
                    a0 = fmaf(hv.x, w[k + 0], a0); a1 = fmaf(hv.x, wB[k + 0], a1);
                    a0 = fmaf(hv.y, w[k + 1], a0); a1 = fmaf(hv.y, wB[k + 1], a1);
                    a0 = fmaf(hv.z, w[k + 2], a0); a1 = fmaf(hv.z, wB[k + 2], a1);
                    a0 = fmaf(hv.w, w[k + 3], a0); a1 = fmaf(hv.w, wB[k + 3], a1);
                }
                *(float2*)(outb + (size_t)r * VOCAB) = make_float2(a0, a1);
            }
        }
        __syncthreads();
    }
}

extern "C" void kernel_launch(void* const* d_in, const int* in_sizes, int n_in,
                              void* d_out, int out_size, void* d_ws, size_t ws_size,
                              hipStream_t stream) {
    const int*   inputs = (const int*)  d_in[0];
    const float* emb    = (const float*)d_in[1];
    const float* W_ih   = (const float*)d_in[2];
    const float* W_hh   = (const float*)d_in[3];
    const float* b_ih   = (const float*)d_in[4];
    const float* b_hh   = (const float*)d_in[5];
    const float* W_out  = (const float*)d_in[6];
    const float* b_out  = (const float*)d_in[7];
    float* out = (float*)d_out;

    float* P = (float*)d_ws;   // 10240 B table

    build_table<<<(VOCAB * HID + 255) / 256, 256, 0, stream>>>(emb, W_ih, b_ih, b_hh, P);
    rnn_fused<<<BATCH, 256, 0, stream>>>(inputs, W_hh, P, W_out, b_out, out);
}

// Round 5
// 419.595 us; speedup vs baseline: 1.1362x; 1.1362x over previous
//
#include <hip/hip_runtime.h>

#define VOCAB 128
#define EMB   10
#define HID   20
#define BATCH 256
#define TLEN  2048
// tanh(x) = 1 - 2/(exp(2x)+1); v_exp_f32 computes 2^z, so fold 2*log2(e)
// into the weights/tables:  z = PRESCALE * (xw + W_hh h)
// RECURRENCE IS CARRIED IN r = 1/(2^z + 1)  (h = 1 - 2r):
//   z_j = [P(tok)_j] + sum_k (-2*PRESCALE*W_hh[j,k]) * r_k
// where P already contains PRESCALE*(biases + emb.W_ih + sum_k W_hh[j,k]).
// Consumers fold h=1-2r into their weights: out = (b+sum_j Wout) - 2*Wout.r
#define PRESCALE 2.8853900817779268f

// ---------------------------------------------------------------------------
// Kernel A: P[v][j] = PRESCALE*(b_ih[j]+b_hh[j]+sum_e W_ih[j,e]*emb[v,e]
//                              + sum_k W_hh[j,k])
// ---------------------------------------------------------------------------
__global__ __launch_bounds__(256)
void build_table(const float* __restrict__ emb, const float* __restrict__ W_ih,
                 const float* __restrict__ W_hh,
                 const float* __restrict__ b_ih, const float* __restrict__ b_hh,
                 float* __restrict__ P) {
    int idx = blockIdx.x * blockDim.x + threadIdx.x;
    if (idx < VOCAB * HID) {
        int v = idx / HID, j = idx % HID;
        float acc = b_ih[j] + b_hh[j];
        #pragma unroll
        for (int e = 0; e < EMB; ++e)
            acc = fmaf(W_ih[j * EMB + e], emb[v * EMB + e], acc);
        float wsum = 0.f;
        #pragma unroll
        for (int k = 0; k < HID; ++k) wsum += W_hh[j * HID + k];
        P[idx] = (acc + wsum) * PRESCALE;
    }
}

// ---------------------------------------------------------------------------
// Fused kernel: one block per batch row, 4 waves (one per SIMD).
//   wave 0  : sequential recurrence in r-space. Per step, PHASE-SEPARATED:
//             (1) 20 back-to-back readlanes of r -> scalars (one hazard, not 20)
//             (2) 4x5 fma chains on long-ready scalar operands
//             (3) tree + exp2 + rcp tail; store r (off-chain).
//   waves1-3: consume chunk c-1 while wave 0 produces chunk c. h=1-2r is
//             folded into consumer weights/bias -> zero per-step cost.
// ---------------------------------------------------------------------------
#define RNN_STEP(XW) { \
    const int ri_ = __float_as_int(r); \
    float bc[HID]; \
    _Pragma("unroll") \
    for (int k = 0; k < HID; ++k) \
        bc[k] = __int_as_float(__builtin_amdgcn_readlane(ri_, k)); \
    float a0 = (XW), a1 = 0.f, a2 = 0.f, a3 = 0.f; \
    _Pragma("unroll") \
    for (int k = 0; k < HID; k += 4) { \
        a0 = fmaf(w[k + 0], bc[k + 0], a0); \
        a1 = fmaf(w[k + 1], bc[k + 1], a1); \
        a2 = fmaf(w[k + 2], bc[k + 2], a2); \
        a3 = fmaf(w[k + 3], bc[k + 3], a3); } \
    float z_ = (a0 + a1) + (a2 + a3); \
    float u_ = __builtin_amdgcn_exp2f(z_); \
    r = __builtin_amdgcn_rcpf(u_ + 1.0f); }

__global__ __launch_bounds__(256)
void rnn_fused(const int* __restrict__ tokens, const float* __restrict__ W_hh,
               const float* __restrict__ P, const float* __restrict__ W_out,
               const float* __restrict__ b_out, float* __restrict__ out) {
    __shared__ float Pl[VOCAB * HID];               // 10240 B
    __shared__ __align__(16) int tok[TLEN + 16];    //  8256 B (pad for prefetch overrun)
    __shared__ float hbuf[2][64][64];               // 32768 B of r-values,
                                                    // row stride 64; cols 0..19 used
    const int tid  = threadIdx.x;
    const int lane = tid & 63;
    const int wid  = tid >> 6;
    const int b    = blockIdx.x;

    // cooperative staging (all 256 threads)
    for (int i = tid; i < VOCAB * HID; i += 256) Pl[i] = P[i];
    const int4* src = (const int4*)(tokens + (size_t)b * TLEN);
    int4* dst = (int4*)tok;
    for (int i = tid; i < TLEN / 4; i += 256) dst[i] = src[i];
    if (tid < 16) tok[TLEN + tid] = 0;

    // per-role register init (before the staging barrier: global reads only)
    const int j = (lane & 31) < HID ? (lane & 31) : HID - 1;  // clamp: dup row 19
    float w[HID], wB[HID];
    float bo0 = 0.f, bo1 = 0.f;
    if (wid == 0) {
        #pragma unroll
        for (int k = 0; k < HID; ++k)
            w[k] = W_hh[j * HID + k] * (-2.0f * PRESCALE);
    } else {
        const int v0 = 2 * lane, v1 = 2 * lane + 1;
        float s0 = 0.f, s1 = 0.f;
        #pragma unroll
        for (int k = 0; k < HID; ++k) {
            float wa = W_out[v0 * HID + k], wb = W_out[v1 * HID + k];
            s0 += wa; s1 += wb;
            w[k]  = -2.0f * wa;
            wB[k] = -2.0f * wb;
        }
        bo0 = b_out[v0] + s0; bo1 = b_out[v1] + s1;
    }
    __syncthreads();

    // producer pipeline prologue: tokens for steps 0..15, xw for steps 0..7
    float r = 0.5f;                                  // h0 = 0  <=>  r0 = 0.5
    int4 ta, tb, tkc, tkd;
    float xw0[4], xw1[4];
    if (wid == 0) {
        __builtin_amdgcn_s_setprio(1);               // critical-path wave
        ta  = *(const int4*)&tok[0];
        tb  = *(const int4*)&tok[4];
        tkc = *(const int4*)&tok[8];
        tkd = *(const int4*)&tok[12];
        xw0[0] = Pl[ta.x * HID + j]; xw0[1] = Pl[ta.y * HID + j];
        xw0[2] = Pl[ta.z * HID + j]; xw0[3] = Pl[ta.w * HID + j];
        xw1[0] = Pl[tb.x * HID + j]; xw1[1] = Pl[tb.y * HID + j];
        xw1[2] = Pl[tb.z * HID + j]; xw1[3] = Pl[tb.w * HID + j];
    }

    // 33-iteration pipeline: iter c -> wave0 produces chunk c, waves1-3
    // consume chunk c-1 from the other LDS buffer half.
    for (int c = 0; c < 33; ++c) {
        if (wid == 0 && c < 32) {
            float* hb = &hbuf[c & 1][0][lane];
            for (int t8 = 0; t8 < 64; t8 += 8) {
                const int t = c * 64 + t8;
                float* hrow = hb + t8 * 64;
                // ---- group 0: steps t..t+3 ----
                RNN_STEP(xw0[0]); hrow[0 * 64] = r;
                RNN_STEP(xw0[1]); hrow[1 * 64] = r;
                RNN_STEP(xw0[2]); hrow[2 * 64] = r;
                RNN_STEP(xw0[3]); hrow[3 * 64] = r;
                // refill xw0 for steps t+8..t+11 (latency hidden by group 1)
                float n0[4] = {Pl[tkc.x * HID + j], Pl[tkc.y * HID + j],
                               Pl[tkc.z * HID + j], Pl[tkc.w * HID + j]};
                tkc = *(const int4*)&tok[t + 16];
                // ---- group 1: steps t+4..t+7 ----
                RNN_STEP(xw1[0]); hrow[4 * 64] = r;
                RNN_STEP(xw1[1]); hrow[5 * 64] = r;
                RNN_STEP(xw1[2]); hrow[6 * 64] = r;
                RNN_STEP(xw1[3]); hrow[7 * 64] = r;
                // refill xw1 for steps t+12..t+15
                float n1[4] = {Pl[tkd.x * HID + j], Pl[tkd.y * HID + j],
                               Pl[tkd.z * HID + j], Pl[tkd.w * HID + j]};
                tkd = *(const int4*)&tok[t + 20];
                #pragma unroll
                for (int u = 0; u < 4; ++u) { xw0[u] = n0[u]; xw1[u] = n1[u]; }
            }
        }
        if (wid > 0 && c > 0) {
            const int cc = c - 1;
            const float* hb = &hbuf[cc & 1][0][0];
            float* outb = out + ((size_t)b * TLEN + (size_t)cc * 64) * VOCAB + 2 * lane;
            for (int rr = wid - 1; rr < 64; rr += 3) {
                const float* hr = hb + rr * 64;
                float a0 = bo0, a1 = bo1;
                #pragma unroll
                for (int k = 0; k < HID; k += 4) {
                    float4 hv = *(const float4*)(hr + k);   // wave-uniform broadcast
                    a0 = fmaf(hv.x, w[k + 0], a0); a1 = fmaf(hv.x, wB[k + 0], a1);
                    a0 = fmaf(hv.y, w[k + 1], a0); a1 = fmaf(hv.y, wB[k + 1], a1);
                    a0 = fmaf(hv.z, w[k + 2], a0); a1 = fmaf(hv.z, wB[k + 2], a1);
                    a0 = fmaf(hv.w, w[k + 3], a0); a1 = fmaf(hv.w, wB[k + 3], a1);
                }
                *(float2*)(outb + (size_t)rr * VOCAB) = make_float2(a0, a1);
            }
        }
        __syncthreads();
    }
}

extern "C" void kernel_launch(void* const* d_in, const int* in_sizes, int n_in,
                              void* d_out, int out_size, void* d_ws, size_t ws_size,
                              hipStream_t stream) {
    const int*   inputs = (const int*)  d_in[0];
    const float* emb    = (const float*)d_in[1];
    const float* W_ih   = (const float*)d_in[2];
    const float* W_hh   = (const float*)d_in[3];
    const float* b_ih   = (const float*)d_in[4];
    const float* b_hh   = (const float*)d_in[5];
    const float* W_out  = (const float*)d_in[6];
    const float* b_out  = (const float*)d_in[7];
    float* out = (float*)d_out;

    float* P = (float*)d_ws;   // 10240 B table

    build_table<<<(VOCAB * HID + 255) / 256, 256, 0, stream>>>(emb, W_ih, W_hh,
                                                               b_ih, b_hh, P);
    rnn_fused<<<BATCH, 256, 0, stream>>>(inputs, W_hh, P, W_out, b_out, out);
}